// Round 7
// baseline (422.356 us; speedup 1.0000x reference)
//
#include <hip/hip_runtime.h>

// VanillaRNN: S=512, I=1, H=256, C=10, B=2048, fp32 in/out.
// R13: 4-wave structure — halve per-CU LDS traffic, engineer out R5's wall.
// Six-round model: per-CU per-step LDS delivery = waves/CU x 8KB (every wave
// reads its col-group's full h; duplicate addrs don't help (R7), swizzles
// don't matter (R8/R12: conflict counter invariant = multi-pass artifact),
// pipelining/stagger/ILP-across-groups all null (R9/R11/R12)). 8 waves ->
// 64KB -> ~850-1150cyc of 1366. Only lever left: FEWER waves/CU.
// Old R5 (4 waves) = 1712cyc, diagnosed: 16-deep dependent MFMA chain at
// latency (~320cy), exposed read latency, unhidden trans at 1 wave/SIMD.
// Fixes here: (1) 8 independent MFMA chains (4 m-tiles x 2 K-halves, 4-deep,
// merge add) -> dep path ~80cy; (2) waves_per_eu(1,1) -> ~512 VGPR budget
// for ~240 demand (afrag 128 + bfr 32 + acc 32 + bias/wxv 32), no R10 spill;
// (3) LDS inflated >80KB (xs pitch 41) so exactly 1 block/CU -> per-CU
// traffic really is 32KB (2 blocks/CU would restore 64KB).
// Kept from R12: linear pitch-264 hT (bank-even reads+writes, lane-invariant
// read stride -> offset immediates; absmax 0.0039), x folded into MFMA C,
// x prefetch, weights pre-scaled by 2*log2e: tanh = 1 - 2*rcp(exp2(s)+1).

#define SEQ    512
#define HID    256
#define NCLS   10
#define BN     16     // batch per block
#define NT     256    // 4 waves
#define XP     41     // xs pitch: odd (bank spread) + inflates LDS past 80KB
#define PITCH  264    // f16 per column (528 B = 33 x 16B chunks)

typedef _Float16 f16x8 __attribute__((ext_vector_type(8)));
typedef _Float16 f16x4 __attribute__((ext_vector_type(4)));
typedef float    f32x4 __attribute__((ext_vector_type(4)));

#define MFMA16(a, b, c) __builtin_amdgcn_mfma_f32_16x16x32_f16(a, b, c, 0, 0, 0)

__global__ __launch_bounds__(NT)
__attribute__((amdgpu_waves_per_eu(1, 1)))
void rnn_mfma(
    const float* __restrict__ x,     // [B, S]
    const float* __restrict__ W_hx,  // [H]
    const float* __restrict__ W_hh,  // [H, H]
    const float* __restrict__ W_ph,  // [C, H]
    const float* __restrict__ b_h,   // [H]
    const float* __restrict__ b_p,   // [C]
    float* __restrict__ out)         // [B, C]
{
    // hT[buf][n][j]: h element (row j, col n) at f16 index j (linear),
    // row pitch 264 f16 -> bank-even reads and writes.
    __shared__ __align__(16) _Float16 hT[2][BN][PITCH];   // 16.5 KB
    __shared__ __align__(16) float xs[SEQ + 2][XP];       // 84.3 KB (>80: 1 blk/CU)

    const int tid  = threadIdx.x;
    const int lane = tid & 63;
    const int wave = tid >> 6;       // 0..3, owns rows [wave*64, wave*64+64)
    const int n16  = lane & 15;
    const int quad = lane >> 4;      // 0..3
    const int b0   = blockIdx.x * BN;

    const float SC = 2.885390081777926814f;   // 2*log2(e)

    // ---- A-frags: 4 m-tiles, rows wave*64 + mt*16 + n16, scaled, f16 ----
    f16x8 afrag[4][8];               // 128 VGPRs
#pragma unroll
    for (int mt = 0; mt < 4; ++mt) {
        const int row = wave * 64 + mt * 16 + n16;
#pragma unroll
        for (int ks = 0; ks < 8; ++ks) {
            const float4* p = (const float4*)&W_hh[row * HID + ks * 32 + quad * 8];
            float4 u = p[0], v = p[1];
            f16x8 a;
            a[0] = (_Float16)(SC * u.x); a[1] = (_Float16)(SC * u.y);
            a[2] = (_Float16)(SC * u.z); a[3] = (_Float16)(SC * u.w);
            a[4] = (_Float16)(SC * v.x); a[5] = (_Float16)(SC * v.y);
            a[6] = (_Float16)(SC * v.z); a[7] = (_Float16)(SC * v.w);
            afrag[mt][ks] = a;
        }
    }
    // D rows for this lane: row = wave*64 + mt*16 + quad*4 + r
    f32x4 bias[4], wxv[4];
#pragma unroll
    for (int mt = 0; mt < 4; ++mt)
#pragma unroll
        for (int r = 0; r < 4; ++r) {
            const int row = wave * 64 + mt * 16 + quad * 4 + r;
            bias[mt][r] = SC * b_h[row];
            wxv[mt][r]  = SC * W_hx[row];
        }

    // ---- linear byte bases; immediates do the rest ----
    // read:  col n16, k-chunk ks (rows ks*32+quad*8..+7) -> rbase + ks*64
    // write: col n16, rows wave*64 + mt*16 + quad*4 + r  -> wbase + mt*32
    const int rbase = n16 * (PITCH * 2) + quad * 16;
    const int wbase = n16 * (PITCH * 2) + wave * 128 + quad * 8;

    // ---- stage xs[t][n] = x[b0+n][t] ----
    for (int i = tid; i < BN * SEQ / 4; i += NT) {
        const int n = i >> 7, t4 = (i & 127) * 4;
        float4 v = *(const float4*)&x[(b0 + n) * SEQ + t4];
        xs[t4 + 0][n] = v.x; xs[t4 + 1][n] = v.y;
        xs[t4 + 2][n] = v.z; xs[t4 + 3][n] = v.w;
    }
    // ---- h0 = 0 (buffer 0 only; buffer 1 fully written each odd step) ----
    for (int i = tid; i < BN * PITCH / 2; i += NT) ((float*)hT[0])[i] = 0.0f;
    __syncthreads();

    float xv = xs[0][n16];   // prefetched x_t for step 0

#define RNN_STEP(T, RD, WR)                                                   \
    {                                                                         \
        const float xnxt = xs[(T) + 1][n16];  /* prefetch next step's x */    \
        const char* rb = (const char*)hT[RD] + rbase;                         \
        char*       wb = (char*)hT[WR] + wbase;                               \
        f16x8 f0 = *(const f16x8*)(rb + 0 * 64);                              \
        f16x8 f1 = *(const f16x8*)(rb + 1 * 64);                              \
        f16x8 f2 = *(const f16x8*)(rb + 2 * 64);                              \
        f16x8 f3 = *(const f16x8*)(rb + 3 * 64);                              \
        f16x8 f4 = *(const f16x8*)(rb + 4 * 64);                              \
        f16x8 f5 = *(const f16x8*)(rb + 5 * 64);                              \
        f16x8 f6 = *(const f16x8*)(rb + 6 * 64);                              \
        f16x8 f7 = *(const f16x8*)(rb + 7 * 64);                              \
        f32x4 e[4], o[4];   /* 8 independent 4-deep chains */                 \
        _Pragma("unroll")                                                     \
        for (int mt = 0; mt < 4; ++mt) {                                      \
            f32x4 c0;                                                         \
            _Pragma("unroll")                                                 \
            for (int r = 0; r < 4; ++r)                                       \
                c0[r] = fmaf(wxv[mt][r], xv, bias[mt][r]);                    \
            e[mt] = MFMA16(afrag[mt][0], f0, c0);                             \
        }                                                                     \
        _Pragma("unroll")                                                     \
        for (int mt = 0; mt < 4; ++mt)                                        \
            o[mt] = MFMA16(afrag[mt][4], f4, (f32x4)0.0f);                    \
        _Pragma("unroll")                                                     \
        for (int mt = 0; mt < 4; ++mt)                                        \
            e[mt] = MFMA16(afrag[mt][1], f1, e[mt]);                          \
        _Pragma("unroll")                                                     \
        for (int mt = 0; mt < 4; ++mt)                                        \
            o[mt] = MFMA16(afrag[mt][5], f5, o[mt]);                          \
        _Pragma("unroll")                                                     \
        for (int mt = 0; mt < 4; ++mt)                                        \
            e[mt] = MFMA16(afrag[mt][2], f2, e[mt]);                          \
        _Pragma("unroll")                                                     \
        for (int mt = 0; mt < 4; ++mt)                                        \
            o[mt] = MFMA16(afrag[mt][6], f6, o[mt]);                          \
        _Pragma("unroll")                                                     \
        for (int mt = 0; mt < 4; ++mt)                                        \
            e[mt] = MFMA16(afrag[mt][3], f3, e[mt]);                          \
        _Pragma("unroll")                                                     \
        for (int mt = 0; mt < 4; ++mt)                                        \
            o[mt] = MFMA16(afrag[mt][7], f7, o[mt]);                          \
        _Pragma("unroll")                                                     \
        for (int mt = 0; mt < 4; ++mt) {                                      \
            f16x4 h4;                                                         \
            _Pragma("unroll")                                                 \
            for (int r = 0; r < 4; ++r) {                                     \
                float s  = e[mt][r] + o[mt][r];                               \
                float ex = __builtin_amdgcn_exp2f(s);                         \
                float rc = __builtin_amdgcn_rcpf(ex + 1.0f);                  \
                h4[r] = (_Float16)(1.0f - 2.0f * rc);                         \
            }                                                                 \
            *(f16x4*)(wb + mt * 32) = h4;                                     \
        }                                                                     \
        xv = xnxt;                                                            \
        __syncthreads();                                                      \
    }

    for (int t = 0; t < SEQ; t += 2) {
        RNN_STEP(t, 0, 1)
        RNN_STEP(t + 1, 1, 0)
    }
#undef RNN_STEP

    // ---- output: out[b][c] = b_p[c] + sum_j W_ph[c][j] * h_final[j][b] ----
    // final h in hT[0]; linear: element (col b, row j) at hT[0][b][j]
    if (tid < BN * NCLS) {
        const int b = tid / NCLS, c = tid % NCLS;
        float sum = b_p[c];
        const _Float16* hp = hT[0][b];
        for (int j = 0; j < HID; ++j)
            sum += W_ph[c * HID + j] * (float)hp[j];
        out[(b0 + b) * NCLS + c] = sum;
    }
}

extern "C" void kernel_launch(void* const* d_in, const int* in_sizes, int n_in,
                              void* d_out, int out_size, void* d_ws, size_t ws_size,
                              hipStream_t stream) {
    const float* x    = (const float*)d_in[0];
    const float* W_hx = (const float*)d_in[1];
    const float* W_hh = (const float*)d_in[2];
    const float* W_ph = (const float*)d_in[3];
    const float* b_h  = (const float*)d_in[4];
    const float* b_p  = (const float*)d_in[5];
    float* out = (float*)d_out;

    rnn_mfma<<<dim3(2048 / BN), dim3(NT), 0, stream>>>(
        x, W_hx, W_hh, W_ph, b_h, b_p, out);
}